// Round 1
// baseline (916.666 us; speedup 1.0000x reference)
//
#include <hip/hip_runtime.h>

#define BB 1024
#define TT 128
#define NBLK 256
#define POISON64 0x7FC07FC07FC07FC0ULL

using bf16   = __bf16;
using bf16x8 = __attribute__((ext_vector_type(8))) bf16;
using f32x4  = __attribute__((ext_vector_type(4))) float;

__device__ __forceinline__ float fsig(float x) {
  return __builtin_amdgcn_rcpf(1.f + __expf(-x));
}
__device__ __forceinline__ float ftanh(float x) {
  return 2.f * __builtin_amdgcn_rcpf(1.f + __expf(-2.f * x)) - 1.f;
}

// ---- coherent (cross-XCD, IF$-served) load/store helpers -------------------
__device__ __forceinline__ void st_u32_coh(unsigned* p, unsigned v) {
  __hip_atomic_store(p, v, __ATOMIC_RELAXED, __HIP_MEMORY_SCOPE_AGENT);
}
__device__ __forceinline__ unsigned ld_u32_coh(const unsigned* p) {
  return __hip_atomic_load((unsigned*)p, __ATOMIC_RELAXED, __HIP_MEMORY_SCOPE_AGENT);
}
__device__ __forceinline__ float ld_f32_coh(const float* p) {
  return __hip_atomic_load((float*)p, __ATOMIC_RELAXED, __HIP_MEMORY_SCOPE_AGENT);
}
__device__ __forceinline__ void st_f32_coh(float* p, float v) {
  __hip_atomic_store(p, v, __ATOMIC_RELAXED, __HIP_MEMORY_SCOPE_AGENT);
}
__device__ __forceinline__ void st_u16_coh(unsigned short* p, unsigned short v) {
  __hip_atomic_store(p, v, __ATOMIC_RELAXED, __HIP_MEMORY_SCOPE_AGENT);
}
__device__ __forceinline__ unsigned long long ld_u64_coh(const void* p) {
  return __hip_atomic_load((unsigned long long*)p, __ATOMIC_RELAXED, __HIP_MEMORY_SCOPE_AGENT);
}
// true iff any bf16 halfword of v equals the poison pattern (no false negatives;
// borrow-induced false positives require another halfword to BE poison — harmless)
__device__ __forceinline__ bool haspoison(unsigned long long v) {
  unsigned long long x = v ^ POISON64;
  return ((x - 0x0001000100010001ULL) & ~x & 0x8000800080008000ULL) != 0ULL;
}

// ---------------------------------------------------------------------------
// prep_a: poison h step-buffers (2048 blocks), softmax, bias, G0, zero slots
// ---------------------------------------------------------------------------
__global__ void prep_a(const float* __restrict__ mem,
                       const float* __restrict__ b_ih, const float* __restrict__ b_hh,
                       const float* __restrict__ rv0, const float* __restrict__ W_ih,
                       bf16* __restrict__ hbufs, float* __restrict__ mem_sm,
                       float* __restrict__ bias, float* __restrict__ G0,
                       unsigned* __restrict__ slots) {
  const int bid = blockIdx.x, tid = threadIdx.x;
  if (bid < 2048) {
    // 128 step-buffers x 256 KB = 33,554,432 B total; 16,384 B per block
    char* base = (char*)hbufs + (size_t)bid * 16384 + tid * 16;
#pragma unroll
    for (int ps = 0; ps < 4; ++ps) {
      unsigned long long* p = (unsigned long long*)(base + ps * 4096);
      p[0] = POISON64; p[1] = POISON64;
    }
  } else if (bid == 2048) {
    if (tid < 128) {
      float mx = -1e30f;
      for (int m = 0; m < 128; ++m) mx = fmaxf(mx, mem[m * 128 + tid]);
      float s = 0.f;
      for (int m = 0; m < 128; ++m) s += __expf(mem[m * 128 + tid] - mx);
      float inv = 1.f / s;
      for (int m = 0; m < 128; ++m) mem_sm[m * 128 + tid] = __expf(mem[m * 128 + tid] - mx) * inv;
    }
  } else if (bid == 2049) {
    for (int e = tid; e < 512; e += 256) bias[e] = b_ih[e] + b_hh[e];
  } else if (bid < 2052) {
    int g = (bid - 2050) * 256 + tid;  // 0..511
    float acc = 0.f;
    for (int k = 0; k < 512; ++k) acc += rv0[k] * W_ih[(size_t)g * 768 + 256 + k];
    G0[g] = acc;
  } else {
    for (int e = tid; e < 4096; e += 256) slots[e] = 0u;
  }
}

// ---------------------------------------------------------------------------
// prep_b: WM[g][r*128+n] = sum_m W_ih[g][256+r*128+m]*mem_sm[m][n]  (512 blocks)
//         FM (block 512)
// ---------------------------------------------------------------------------
__global__ void prep_b(const float* __restrict__ W_ih, const float* __restrict__ fc_w,
                       const float* __restrict__ mem_sm,
                       bf16* __restrict__ WMg, float* __restrict__ FM) {
  const int bid = blockIdx.x, tid = threadIdx.x;
  if (bid < 512) {
    __shared__ float sW[512];
    const int g = bid;
    for (int e = tid; e < 512; e += 256) sW[e] = W_ih[(size_t)g * 768 + 256 + e];
    __syncthreads();
    const int r = tid >> 6, n0 = (tid & 63) * 2;
    float a0 = 0.f, a1 = 0.f;
    const float* wr = sW + r * 128;
#pragma unroll 4
    for (int m = 0; m < 128; ++m) {
      float2 ms = *(const float2*)(mem_sm + m * 128 + n0);
      a0 += wr[m] * ms.x;
      a1 += wr[m] * ms.y;
    }
    union { bf16 h[2]; unsigned u; } pk;
    pk.h[0] = (bf16)a0; pk.h[1] = (bf16)a1;
    *(unsigned*)(WMg + (size_t)g * 512 + r * 128 + n0) = pk.u;
  } else {
    for (int sub = tid; sub < 2 * 512; sub += 256) {
      int o = sub >> 9, rn = sub & 511, rr = rn >> 7, n = rn & 127;
      const float* wr = fc_w + o * 640 + 128 + rr * 128;
      float acc = 0.f;
      for (int m = 0; m < 128; ++m) acc += wr[m] * mem_sm[m * 128 + n];
      FM[o * 512 + rn] = acc;
    }
  }
}

// ---------------------------------------------------------------------------
// persistent main: 256 blocks x 256 threads. No per-step grid barrier:
// h_t lives in a private per-step buffer, pre-poisoned with bf16 NaN; consumers
// poll the exact 8B chunks they need (data == flag). One slot barrier remains
// for the epilogue only.
// ---------------------------------------------------------------------------
__global__ void __launch_bounds__(256, 1) dnc_main(
    const float* __restrict__ x, const bf16* __restrict__ WMg,
    const float* __restrict__ bias, const float* __restrict__ G0,
    const float* __restrict__ FM, bf16* __restrict__ hbufs,
    float* __restrict__ hsumG, unsigned* __restrict__ slots,
    const float* __restrict__ W_ih, const float* __restrict__ W_hh,
    const float* __restrict__ fc_w, const float* __restrict__ fc_b,
    float* __restrict__ out) {
  __shared__ bf16 sWx[32][264];    // Wx  (32 owned gate cols) x K=256, odd granules
  __shared__ bf16 sWhh[32][136];
  __shared__ bf16 sWM[32][520];
  __shared__ bf16 sHq[16][520];    // hquad-major staged tile

  const int bid = blockIdx.x, tid = threadIdx.x;
  const int rt = bid >> 4, gt = bid & 15;
  const int wave = tid >> 6, lane = tid & 63;
  const int l15 = lane & 15, l4 = lane >> 4;

  auto gcol = [&](int pos) { return ((pos >> 3) << 7) + gt * 8 + (pos & 7); };

  // one-time weight staging into LDS
  for (int e = tid; e < 32 * 256; e += 256) sWx[e >> 8][e & 255] = (bf16)W_ih[(size_t)gcol(e >> 8) * 768 + (e & 255)];
  for (int e = tid; e < 32 * 128; e += 256) sWhh[e >> 7][e & 127] = (bf16)W_hh[gcol(e >> 7) * 128 + (e & 127)];
  for (int e = tid; e < 32 * 512; e += 256) sWM[e >> 9][e & 511] = WMg[(size_t)gcol(e >> 9) * 512 + (e & 511)];
  __syncthreads();

  const float bv0 = bias[gcol(l15)], bv1 = bias[gcol(16 + l15)];

  const bool lo = (l15 < 8);
  const int j = l15 & 7;
  const int rb = lo ? 0 : 2;
  float cst[2] = {0.f, 0.f}, hsum[2] = {0.f, 0.f};
  int growp[2];
#pragma unroll
  for (int k = 0; k < 2; ++k) growp[k] = rt * 16 + (l4 * 4 + rb + k) + 256 * wave;

  // batch row this thread's A-fragment comes from; x row base (x is [B,T,256])
  const float* xrow = x + (size_t)(rt * 16 + l15 + 256 * wave) * (TT * 256);

  f32x4 acc0, acc1;

  auto xpart = [&](int t) {
    acc0 = f32x4{bv0, bv0, bv0, bv0};
    acc1 = f32x4{bv1, bv1, bv1, bv1};
    const float* xr = xrow + (size_t)t * 256 + l4 * 8;
#pragma unroll
    for (int kk = 0; kk < 8; ++kk) {
      float4 u0 = *(const float4*)(xr + kk * 32);
      float4 u1 = *(const float4*)(xr + kk * 32 + 4);
      bf16x8 a;
      a[0] = (bf16)u0.x; a[1] = (bf16)u0.y; a[2] = (bf16)u0.z; a[3] = (bf16)u0.w;
      a[4] = (bf16)u1.x; a[5] = (bf16)u1.y; a[6] = (bf16)u1.z; a[7] = (bf16)u1.w;
      bf16x8 w0 = *(const bf16x8*)&sWx[l15][kk * 32 + l4 * 8];
      bf16x8 w1 = *(const bf16x8*)&sWx[16 + l15][kk * 32 + l4 * 8];
      acc0 = __builtin_amdgcn_mfma_f32_16x16x32_bf16(a, w0, acc0, 0, 0, 0);
      acc1 = __builtin_amdgcn_mfma_f32_16x16x32_bf16(a, w1, acc1, 0, 0, 0);
    }
  };

  auto hpart = [&](const bf16* hrd) {
    // all 16 u64 chunks of h_{t-1} this thread needs:
    //   i=0..7  : Whh A-rows (own batch rows)
    //   i=8..15 : hquad staging chunks (rows rt*64 + (tid>>4) + 16*pass)
    const bf16* hr  = hrd + (size_t)(rt * 16 + l15 + 256 * wave) * 128 + l4 * 8;
    const bf16* hs0 = hrd + (size_t)(rt * 64 + (tid >> 4)) * 128 + (tid & 15) * 8;
    unsigned long long v[16];
#pragma unroll
    for (int i = 0; i < 16; ++i) {
      const bf16* p = (i < 8) ? (hr + (i >> 1) * 32 + (i & 1) * 4)
                              : (hs0 + (size_t)((i - 8) >> 1) * 2048 + (i & 1) * 4);
      v[i] = ld_u64_coh(p);
    }
    // batched poll: reload only stale chunks (values are write-once, so a
    // non-poison observation is final)
    for (;;) {
      unsigned stale = 0;
#pragma unroll
      for (int i = 0; i < 16; ++i) stale |= haspoison(v[i]) ? (1u << i) : 0u;
      if (!stale) break;
      __builtin_amdgcn_s_sleep(1);
#pragma unroll
      for (int i = 0; i < 16; ++i)
        if (stale & (1u << i)) {
          const bf16* p = (i < 8) ? (hr + (i >> 1) * 32 + (i & 1) * 4)
                                  : (hs0 + (size_t)((i - 8) >> 1) * 2048 + (i & 1) * 4);
          v[i] = ld_u64_coh(p);
        }
    }
    // Whh MFMAs (register-only inputs; safe before the sHq hazard barrier)
#pragma unroll
    for (int kk = 0; kk < 4; ++kk) {
      union { unsigned long long u[2]; bf16x8 b; } c;
      c.u[0] = v[2 * kk]; c.u[1] = v[2 * kk + 1];
      bf16x8 w0 = *(const bf16x8*)&sWhh[l15][kk * 32 + l4 * 8];
      bf16x8 w1 = *(const bf16x8*)&sWhh[16 + l15][kk * 32 + l4 * 8];
      acc0 = __builtin_amdgcn_mfma_f32_16x16x32_bf16(c.b, w0, acc0, 0, 0, 0);
      acc1 = __builtin_amdgcn_mfma_f32_16x16x32_bf16(c.b, w1, acc1, 0, 0, 0);
    }
    __syncthreads();  // all waves done reading prev-step sHq
#pragma unroll
    for (int pass = 0; pass < 4; ++pass) {
      int row = (tid >> 4) + 16 * pass, seg = tid & 15;
      union { unsigned long long u[2]; bf16x8 b; } c;
      c.u[0] = v[8 + 2 * pass]; c.u[1] = v[9 + 2 * pass];
      *(bf16x8*)&sHq[row >> 2][(row & 3) * 128 + seg * 8] = c.b;
    }
    __syncthreads();  // sHq ready
#pragma unroll
    for (int kk = 0; kk < 16; ++kk) {
      bf16x8 a  = *(const bf16x8*)&sHq[l15][kk * 32 + l4 * 8];
      bf16x8 w0 = *(const bf16x8*)&sWM[l15][kk * 32 + l4 * 8];
      bf16x8 w1 = *(const bf16x8*)&sWM[16 + l15][kk * 32 + l4 * 8];
      acc0 = __builtin_amdgcn_mfma_f32_16x16x32_bf16(a, w0, acc0, 0, 0, 0);
      acc1 = __builtin_amdgcn_mfma_f32_16x16x32_bf16(a, w1, acc1, 0, 0, 0);
    }
  };

  auto pw = [&](bool add_g0, bf16* hwr) {
    float o0[4], o1[4];
#pragma unroll
    for (int r = 0; r < 4; ++r) {
      o0[r] = __shfl_xor(acc0[r], 8);
      o1[r] = __shfl_xor(acc1[r], 8);
    }
    float g0i = 0.f, g0f = 0.f, g0g = 0.f, g0o = 0.f;
    if (add_g0) {
      int cb = gt * 8 + j;
      g0i = G0[cb]; g0f = G0[128 + cb]; g0g = G0[256 + cb]; g0o = G0[384 + cb];
    }
#pragma unroll
    for (int k = 0; k < 2; ++k) {
      int r = rb + k;
      float gi = (lo ? acc0[r] : o0[r]) + g0i;
      float gf = (lo ? o0[r] : acc0[r]) + g0f;
      float gg = (lo ? acc1[r] : o1[r]) + g0g;
      float go = (lo ? o1[r] : acc1[r]) + g0o;
      cst[k] = fsig(gf) * cst[k] + fsig(gi) * ftanh(gg);
      float h = fsig(go) * ftanh(cst[k]);
      hsum[k] += h;
      union { bf16 b; unsigned short u; } cv; cv.b = (bf16)h;
      st_u16_coh((unsigned short*)(hwr + (size_t)growp[k] * 128 + gt * 8 + j), cv.u);
    }
  };

  auto commit = [&](unsigned gen) {
    asm volatile("s_waitcnt vmcnt(0)" ::: "memory");
    __syncthreads();
    if (tid == 0) st_u32_coh(slots + bid * 16, gen);
  };
  auto gridwait = [&](unsigned gen) {
    while (ld_u32_coh(slots + tid * 16) < gen) {}
    __syncthreads();
  };

  // ---- timeline: no grid barrier; per-step private buffers ----------------
  xpart(0);
  pw(true, hbufs);                                    // h_0 -> buf 0
  for (int t = 1; t < TT; ++t) {
    xpart(t);                                         // h-independent overlap
    hpart(hbufs + (size_t)(t - 1) * (BB * 128));      // polls h_{t-1}
    pw(false, hbufs + (size_t)t * (BB * 128));        // writes h_t
  }
  // epilogue: hsum -> global, single slot barrier, fused mean+projection
#pragma unroll
  for (int k = 0; k < 2; ++k)
    st_f32_coh(hsumG + (size_t)growp[k] * 128 + gt * 8 + j, hsum[k]);
  commit(1);
  gridwait(1);
  {
    int row = bid * 4 + wave;
    const float* hsr = hsumG + (size_t)row * 128;
    const float* hqr = hsumG + (size_t)(row & 255) * 512;
    float s0 = 0.f, s1 = 0.f;
    for (int k = lane; k < 128; k += 64) { float v = ld_f32_coh(hsr + k); s0 += v * fc_w[k]; s1 += v * fc_w[640 + k]; }
    for (int k = lane; k < 512; k += 64) { float v = ld_f32_coh(hqr + k); s0 += v * FM[k]; s1 += v * FM[512 + k]; }
    for (int off = 32; off > 0; off >>= 1) { s0 += __shfl_down(s0, off); s1 += __shfl_down(s1, off); }
    if (lane == 0) {
      out[row * 2 + 0] = s0 * (1.f / 128.f) + fc_b[0];
      out[row * 2 + 1] = s1 * (1.f / 128.f) + fc_b[1];
    }
  }
}

// ---------------------------------------------------------------------------
extern "C" void kernel_launch(void* const* d_in, const int* in_sizes, int n_in,
                              void* d_out, int out_size, void* d_ws, size_t ws_size,
                              hipStream_t stream) {
  const float* x      = (const float*)d_in[0];
  const float* memory = (const float*)d_in[1];
  const float* rv0    = (const float*)d_in[2];
  const float* W_ih   = (const float*)d_in[3];
  const float* W_hh   = (const float*)d_in[4];
  const float* b_ih   = (const float*)d_in[5];
  const float* b_hh   = (const float*)d_in[6];
  const float* fc_w   = (const float*)d_in[7];
  const float* fc_b   = (const float*)d_in[8];
  float* out = (float*)d_out;
  char* ws = (char*)d_ws;

  bf16*     hbufs  = (bf16*)ws;                      // 33,554,432 B (128 step bufs)
  bf16*     WMg    = (bf16*)(ws + 33554432);         //    524,288
  float*    mem_sm = (float*)(ws + 34078720);        //     65,536
  float*    bias   = (float*)(ws + 34144256);        //      2,048
  float*    G0     = (float*)(ws + 34146304);        //      2,048
  float*    FM     = (float*)(ws + 34148352);        //      4,096
  unsigned* slots  = (unsigned*)(ws + 34152448);     //     16,384
  float*    hsumG  = (float*)(ws + 34168832);        //    524,288  (end 34,693,120)

  prep_a<<<2053, 256, 0, stream>>>(memory, b_ih, b_hh, rv0, W_ih,
                                   hbufs, mem_sm, bias, G0, slots);
  prep_b<<<513, 256, 0, stream>>>(W_ih, fc_w, mem_sm, WMg, FM);
  dnc_main<<<NBLK, 256, 0, stream>>>(x, WMg, bias, G0, FM, hbufs, hsumG, slots,
                                     W_ih, W_hh, fc_w, fc_b, out);
}